// Round 1
// baseline (139.835 us; speedup 1.0000x reference)
//
#include <hip/hip_runtime.h>
#include <math.h>

typedef float f32x4 __attribute__((ext_vector_type(4)));
typedef int   i32x4 __attribute__((ext_vector_type(4)));
typedef int   i32x8 __attribute__((ext_vector_type(8)));
typedef float f32x2 __attribute__((ext_vector_type(2)));

#define MTOT 16384
#define HALF 8192
#define KDIM 256                  /* bytes per row in fp8 Z */
#define BM 256                    /* tile edge (was 128) */
#define NB (MTOT / BM)            /* 64 block-rows */
#define NBLK (NB * (NB + 1) / 2)  /* 2080 upper-triangle blocks */

#define GLDS16(g, l) __builtin_amdgcn_global_load_lds(                      \
    (const __attribute__((address_space(1))) void*)(g),                     \
    (__attribute__((address_space(3))) void*)(l), 16, 0, 0)

// ---------------------------------------------------------------------------
// Pass 1: fp32 -> fp8 e4m3 (OCP) via HW v_cvt_pk_fp8_f32; per-row squared
// norms computed FROM THE QUANTIZED values so the kernel-matrix diagonal
// cancels to d2 == 0 exactly. Also zero-inits the fused-reduce accumulator
// and completion counter (visible to mmd_gemm via kernel-boundary order).
// ---------------------------------------------------------------------------
__global__ __launch_bounds__(256) void convert_kernel(
    const float* __restrict__ Nmat, const float* __restrict__ Rmat,
    unsigned int* __restrict__ Z, float* __restrict__ x2,
    float* __restrict__ accum, unsigned int* __restrict__ counter) {
  if (blockIdx.x == 0 && threadIdx.x == 0) { *accum = 0.f; *counter = 0u; }
  const int lane = threadIdx.x & 63;
  const int wv = threadIdx.x >> 6;
  const int row = blockIdx.x * 4 + wv;          // 0..16383
  const float* src = (row < HALF) ? (Nmat + (size_t)row * KDIM)
                                  : (Rmat + (size_t)(row - HALF) * KDIM);
  float4 v = *(const float4*)(src + lane * 4);
  int pk = __builtin_amdgcn_cvt_pk_fp8_f32(v.x, v.y, 0, false);
  pk = __builtin_amdgcn_cvt_pk_fp8_f32(v.z, v.w, pk, true);
  Z[(size_t)row * (KDIM / 4) + lane] = (unsigned int)pk;
  f32x2 d01 = __builtin_amdgcn_cvt_pk_f32_fp8(pk, false);
  f32x2 d23 = __builtin_amdgcn_cvt_pk_f32_fp8(pk, true);
  float sq = d01[0] * d01[0] + d01[1] * d01[1] + d23[0] * d23[0] + d23[1] * d23[1];
  #pragma unroll
  for (int off = 32; off; off >>= 1) sq += __shfl_down(sq, off);
  if (lane == 0) x2[row] = sq;
}

// ---------------------------------------------------------------------------
// Pass 2: upper-block-triangular S = Z Z^T via MX-fp8 MFMA, 256x256 tiles.
//
// vs. the 128x128 version (56 us, MfmaUtil 23%): the one-shot stage +
// single-barrier structure convoyed ~1170cy of L2->LDS staging against
// ~1100cy of MFMA per block. Here the tile is 2x larger (halves aggregate
// L2 tile traffic 528->266 MB, doubles FLOPs per staged byte) and staging
// is split into the two K=128 slabs the MFMA consumes anyway:
//     stage slab0 -> barrier (drains ONLY slab0: slab1 not yet issued)
//     issue slab1 -> compute ks=0 (hides slab1's L2 latency)
//     barrier -> compute ks=1
// Only slab0's stage is exposed per block.
//
// LDS per matrix = 2 slabs x [256 rows x 128B]. Within a slab, slot s of
// row r holds global 16B chunk s ^ (r&7): with GLDS16's linear lane*16
// dest, that means lane l of staging instr i sources chunk (l&7)^(l>>3) of
// row i*8+(l>>3) -- and an 8-lane b128 read phase hits all 32 banks.
//
// acc init = -(x2[i]+x2[j])/2 so acc ends as -d2/2; off-diagonal blocks
// prove exp==0 via a 64-wide max (+ __any), exp runs on ~64/2080 blocks.
// Fused finalize: per-block LDS reduce -> one atomicAdd; last block
// (fence + counter) does the mean + sqrt. No third kernel.
// ---------------------------------------------------------------------------
__global__ __launch_bounds__(512, 2) void mmd_gemm(
    const unsigned char* __restrict__ Z, const float* __restrict__ x2,
    float* __restrict__ accum, unsigned int* __restrict__ counter,
    float* __restrict__ out) {
  // XCD-chunked swizzle (2080 % 8 == 0 -> bijective): each XCD gets a
  // contiguous t-range, so blocks sharing a bm panel share one L2.
  const int t = (blockIdx.x & 7) * (NBLK / 8) + (blockIdx.x >> 3);
  const int u = NBLK - 1 - t;
  int rr = (int)((sqrtf(8.0f * (float)u + 1.0f) - 1.0f) * 0.5f);
  while (rr * (rr + 1) / 2 > u) --rr;
  while ((rr + 1) * (rr + 2) / 2 <= u) ++rr;
  const int bm = NB - 1 - rr;
  const int bn = bm + (t - (bm * NB - bm * (bm - 1) / 2));

  __shared__ unsigned char As[2 * BM * 128];   // 64 KB: two 32KB K-slabs
  __shared__ unsigned char Bs[2 * BM * 128];   // 64 KB
  __shared__ float wsred[8];

  const int tid  = threadIdx.x;
  const int lane = tid & 63;
  const int wid  = tid >> 6;       // 0..7
  const int wm   = wid >> 2;       // wave row (0..1), owns 128 rows
  const int wn   = wid & 3;        // wave col (0..3), owns 64 cols

  const unsigned char* Abase = Z + (size_t)bm * BM * KDIM;
  const unsigned char* Bbase = Z + (size_t)bn * BM * KDIM;

  // Staging geometry: instr i covers rows 8i..8i+7 of a slab (8 rows x 8
  // slots = 1 KB). Lane l -> row-in-group lr=l>>3, slot ls=l&7, and the
  // swizzle key is just lr, so the per-lane source offset is i-invariant.
  const int lr = lane >> 3;
  const int ls = lane & 7;
  const int cofs = lr * 256 + ((ls ^ lr) << 4);

  // ---- phase 0: stage K-bytes [0,128) of both tiles (4+4 GLDS / wave)
  #pragma unroll
  for (int tt = 0; tt < 4; ++tt) {
    int i = wid * 4 + tt;                 // wave-uniform instruction id
    GLDS16(Abase + i * 2048 + cofs, As + i * 1024);
    GLDS16(Bbase + i * 2048 + cofs, Bs + i * 1024);
  }

  // While phase-0 is in flight: fragment geometry + x2 loads + acc init.
  const int fr = lane & 15;
  const int fq = lane >> 4;        // 0..3

  float xch[4];
  #pragma unroll
  for (int tn = 0; tn < 4; ++tn)
    xch[tn] = -0.5f * x2[bn * BM + wn * 64 + tn * 16 + fr];

  f32x4 acc[8][4];
  #pragma unroll
  for (int tm = 0; tm < 8; ++tm) {
    float xr[4];
    #pragma unroll
    for (int v = 0; v < 4; ++v)
      xr[v] = -0.5f * x2[bm * BM + wm * 128 + tm * 16 + fq * 4 + v];
    #pragma unroll
    for (int tn = 0; tn < 4; ++tn)
      #pragma unroll
      for (int v = 0; v < 4; ++v)
        acc[tm][tn][v] = xr[v] + xch[tn];
  }

  __syncthreads();   // drains vmcnt: ONLY phase-0 loads exist yet

  // ---- phase 1 issue: K-bytes [128,256) land under ks=0's MFMA work
  #pragma unroll
  for (int tt = 0; tt < 4; ++tt) {
    int i = wid * 4 + tt;
    GLDS16(Abase + i * 2048 + 128 + cofs, As + 32768 + i * 1024);
    GLDS16(Bbase + i * 2048 + 128 + cofs, Bs + 32768 + i * 1024);
  }

  // Fragment reads: lane (fr,fq) needs slab-local chunks 2fq, 2fq+1 of its
  // row; stored at slot c ^ (row&7), row&7 == fr&7.
  const int key = fr & 7;
  const int slotL = ((2 * fq) ^ key) * 16;
  const int slotH = ((2 * fq + 1) ^ key) * 16;

  #pragma unroll
  for (int ks = 0; ks < 2; ++ks) {
    const unsigned char* A_s = As + ks * 32768;
    const unsigned char* B_s = Bs + ks * 32768;
    i32x8 bf[4];
    #pragma unroll
    for (int tn = 0; tn < 4; ++tn) {
      int row = wn * 64 + tn * 16 + fr;
      i32x4 lo = *(const i32x4*)(B_s + row * 128 + slotL);
      i32x4 hi = *(const i32x4*)(B_s + row * 128 + slotH);
      bf[tn] = __builtin_shufflevector(lo, hi, 0, 1, 2, 3, 4, 5, 6, 7);
    }
    #pragma unroll
    for (int tm = 0; tm < 8; ++tm) {
      int row = wm * 128 + tm * 16 + fr;
      i32x4 lo = *(const i32x4*)(A_s + row * 128 + slotL);
      i32x4 hi = *(const i32x4*)(A_s + row * 128 + slotH);
      i32x8 af = __builtin_shufflevector(lo, hi, 0, 1, 2, 3, 4, 5, 6, 7);
      #pragma unroll
      for (int tn = 0; tn < 4; ++tn)
        acc[tm][tn] = __builtin_amdgcn_mfma_scale_f32_16x16x128_f8f6f4(
            af, bf[tn], acc[tm][tn], 0, 0,
            0, 0x7F7F7F7F, 0, 0x7F7F7F7F);
    }
    if (ks == 0) __syncthreads();   // slab-1 staged (barrier drains vmcnt)
  }

  // Epilogue. acc = -d2/2; exp(-d2)==0 in fp32 whenever acc <= -40.
  float amax = -1e30f;
  #pragma unroll
  for (int tm = 0; tm < 8; ++tm)
    #pragma unroll
    for (int tn = 0; tn < 4; ++tn)
      #pragma unroll
      for (int v = 0; v < 4; ++v)
        amax = fmaxf(amax, acc[tm][tn][v]);

  float partial = 0.f;
  if (__any(amax > -40.f)) {       // diagonal blocks + any freak near-pair
    #pragma unroll
    for (int tm = 0; tm < 8; ++tm)
      #pragma unroll
      for (int tn = 0; tn < 4; ++tn)
        #pragma unroll
        for (int v = 0; v < 4; ++v) {
          float a = fminf(acc[tm][tn][v], 0.f);   // clamp d2 >= 0
          partial += exp2f(a * 2.885390082f);     // exp(2a)
        }
  }

  #pragma unroll
  for (int off = 32; off; off >>= 1) partial += __shfl_down(partial, off);
  if (lane == 0) wsred[wid] = partial;
  __syncthreads();

  if (tid == 0) {
    float bsum = 0.f;
    #pragma unroll
    for (int i = 0; i < 8; ++i) bsum += wsred[i];
    // Block weight: sign(N/R half); off-diag blocks x2 (symmetry). Row 8192
    // boundary == block 32, so sign is block-uniform.
    float wgt = ((bm < NB / 2) == (bn < NB / 2)) ? 1.f : -1.f;
    if (bm != bn) wgt *= 2.f;
    atomicAdd(accum, bsum * wgt);
    __threadfence();               // order accum-add before counter bump
    unsigned int old = atomicAdd(counter, 1u);
    if (old == NBLK - 1) {         // last block: all adds are L2-visible
      float tot = atomicAdd(accum, 0.f);   // coherent RMW read
      float mmd = tot / ((float)HALF * (float)HALF);
      out[0] = sqrtf(fmaxf(mmd, 0.f));
    }
  }
}

extern "C" void kernel_launch(void* const* d_in, const int* in_sizes, int n_in,
                              void* d_out, int out_size, void* d_ws, size_t ws_size,
                              hipStream_t stream) {
  const float* Nmat = (const float*)d_in[0];
  const float* Rmat = (const float*)d_in[1];
  float* out = (float*)d_out;

  char* ws = (char*)d_ws;
  unsigned char* Z = (unsigned char*)ws;                       // 4 MiB
  float* x2        = (float*)(ws + (size_t)MTOT * KDIM);       // 64 KiB
  float* accum     = (float*)(ws + (size_t)MTOT * KDIM + (size_t)MTOT * 4);
  unsigned int* counter = (unsigned int*)(ws + (size_t)MTOT * KDIM + (size_t)MTOT * 4 + 4);

  convert_kernel<<<MTOT / 4, 256, 0, stream>>>(Nmat, Rmat, (unsigned int*)Z, x2,
                                               accum, counter);
  mmd_gemm<<<NBLK, 512, 0, stream>>>(Z, x2, accum, counter, out);
}

// Round 2
// 122.033 us; speedup vs baseline: 1.1459x; 1.1459x over previous
//
#include <hip/hip_runtime.h>
#include <math.h>

typedef float f32x4 __attribute__((ext_vector_type(4)));
typedef int   i32x4 __attribute__((ext_vector_type(4)));
typedef int   i32x8 __attribute__((ext_vector_type(8)));
typedef float f32x2 __attribute__((ext_vector_type(2)));

#define MTOT 16384
#define HALF 8192
#define KDIM 256                  /* bytes per row in fp8 Z */
#define BM 256                    /* tile edge */
#define NB (MTOT / BM)            /* 64 block-rows */
#define NBLK (NB * (NB + 1) / 2)  /* 2080 upper-triangle tiles */
#define NBLOCKS 256               /* persistent: 1 block per CU */
#define TPX (NBLK / 8)            /* 260 tiles per XCD */

#define GLDS16(g, l) __builtin_amdgcn_global_load_lds(                      \
    (const __attribute__((address_space(1))) void*)(g),                     \
    (__attribute__((address_space(3))) void*)(l), 16, 0, 0)

/* raw barrier: does NOT drain vmcnt (that is the whole point) */
#define BAR() do { asm volatile("" ::: "memory");                           \
  __builtin_amdgcn_s_barrier(); asm volatile("" ::: "memory"); } while (0)

// ---------------------------------------------------------------------------
// Pass 1: fp32 -> fp8 e4m3 via HW cvt_pk; row norms from the QUANTIZED
// values so the kernel-matrix diagonal cancels exactly. Also zero-inits the
// fused-reduce accumulator + completion counter.
// ---------------------------------------------------------------------------
__global__ __launch_bounds__(256) void convert_kernel(
    const float* __restrict__ Nmat, const float* __restrict__ Rmat,
    unsigned int* __restrict__ Z, float* __restrict__ x2,
    float* __restrict__ accum, unsigned int* __restrict__ counter) {
  if (blockIdx.x == 0 && threadIdx.x == 0) { *accum = 0.f; *counter = 0u; }
  const int lane = threadIdx.x & 63;
  const int wv = threadIdx.x >> 6;
  const int row = blockIdx.x * 4 + wv;          // 0..16383
  const float* src = (row < HALF) ? (Nmat + (size_t)row * KDIM)
                                  : (Rmat + (size_t)(row - HALF) * KDIM);
  float4 v = *(const float4*)(src + lane * 4);
  int pk = __builtin_amdgcn_cvt_pk_fp8_f32(v.x, v.y, 0, false);
  pk = __builtin_amdgcn_cvt_pk_fp8_f32(v.z, v.w, pk, true);
  Z[(size_t)row * (KDIM / 4) + lane] = (unsigned int)pk;
  f32x2 d01 = __builtin_amdgcn_cvt_pk_f32_fp8(pk, false);
  f32x2 d23 = __builtin_amdgcn_cvt_pk_f32_fp8(pk, true);
  float sq = d01[0] * d01[0] + d01[1] * d01[1] + d23[0] * d23[0] + d23[1] * d23[1];
  #pragma unroll
  for (int off = 32; off; off >>= 1) sq += __shfl_down(sq, off);
  if (lane == 0) x2[row] = sq;
}

__device__ __forceinline__ void decode_tile(int t, int& bm, int& bn) {
  const int u = NBLK - 1 - t;
  int rr = (int)((sqrtf(8.0f * (float)u + 1.0f) - 1.0f) * 0.5f);
  while (rr * (rr + 1) / 2 > u) --rr;
  while ((rr + 1) * (rr + 2) / 2 <= u) ++rr;
  bm = NB - 1 - rr;
  bn = bm + (t - (bm * NB - bm * (bm - 1) / 2));
}

// ---------------------------------------------------------------------------
// Pass 2: persistent counted-vmcnt pipeline over the tile stream.
//
// 256 blocks x 512 threads, 1/CU (128 KB LDS). Each block owns ~8 tiles of
// its XCD's contiguous 260-tile range (panels stay in that XCD's L2). The
// K=256 of each 256x256 tile splits into two 64 KB slabs (A-half 32 KB +
// B-half 32 KB); slabs of consecutive tiles form one stream, double-buffered:
//
//   prologue: issue slab0 -> buf0, slab1 -> buf1          (8 GLDS / wave each)
//   iter j:   s_waitcnt vmcnt(8)   -- slab j landed, slab j+1 still in flight
//             s_barrier            -- raw: does NOT drain the prefetch
//             [tid0: deferred wsred reduce of tile (j/2)-1 -> atomicAdd]
//             32 MFMA / wave on buf[j&1]
//             s_barrier            -- all waves done reading buf[j&1]
//             issue slab j+2 -> buf[j&1]   (hides under next compute phase)
//             [j odd: epilogue(tile) -> wsred; acc re-init for next tile]
//
// Steady state never waits vmcnt(0): every slab's 64 KB L2 fetch hides
// under the previous slab's ~2200-cycle MFMA phase (demand 29 B/cy/CU vs
// ~56 B/cy/CU of L2 BW). LDS swizzle identical to the verified round-1
// layout: slot s of row r holds chunk s ^ (r&7); b128 reads conflict-free.
//
// acc init = -(x2[i]+x2[j])/2 so acc ends as -d2/2; off-diagonal tiles
// prove exp==0 via 64-wide max + __any (exp runs on ~64/2080 tiles).
// ---------------------------------------------------------------------------
__global__ __launch_bounds__(512, 2) void mmd_gemm(
    const unsigned char* __restrict__ Z, const float* __restrict__ x2,
    float* __restrict__ accum, unsigned int* __restrict__ counter,
    float* __restrict__ out) {
  __shared__ unsigned char As[2 * 32768];   // two 32 KB A K-slabs
  __shared__ unsigned char Bs[2 * 32768];   // two 32 KB B K-slabs
  __shared__ float wsred[8];

  const int tid  = threadIdx.x;
  const int lane = tid & 63;
  const int wid  = tid >> 6;       // 0..7
  const int wm   = wid >> 2;       // wave row (0..1): 128 output rows
  const int wn   = wid & 3;        // wave col (0..3): 64 output cols

  // staging geometry (swizzle key == row&7 == lane>>3)
  const int lr = lane >> 3;
  const int ls = lane & 7;
  const int cofs = lr * KDIM + ((ls ^ lr) << 4);

  // fragment geometry
  const int fr = lane & 15;
  const int fq = lane >> 4;
  const int key = fr & 7;
  const int slotL = ((2 * fq) ^ key) * 16;
  const int slotH = ((2 * fq + 1) ^ key) * 16;

  const int xcd = blockIdx.x & 7;
  const int lb  = blockIdx.x >> 3;                    // 0..31 within XCD
  const int niter = (lb < (TPX & 31)) ? (TPX / 32 + 1) : (TPX / 32); // 9 or 8
  const int nslab = 2 * niter;

  f32x4 acc[8][4];

  auto STAGE = [&](int bmv, int bnv, int h, int buf) {
    const unsigned char* Ab = Z + (size_t)bmv * (BM * KDIM) + h * 128 + cofs;
    const unsigned char* Bb = Z + (size_t)bnv * (BM * KDIM) + h * 128 + cofs;
    unsigned char* Ad = As + buf * 32768;
    unsigned char* Bd = Bs + buf * 32768;
    #pragma unroll
    for (int tt = 0; tt < 4; ++tt) {
      int i = wid * 4 + tt;                 // wave-uniform instruction id
      GLDS16(Ab + i * 2048, Ad + i * 1024);
      GLDS16(Bb + i * 2048, Bd + i * 1024);
    }
  };

  auto ACCINIT = [&](int bmv, int bnv) {
    float xch[4];
    #pragma unroll
    for (int tn = 0; tn < 4; ++tn)
      xch[tn] = -0.5f * x2[bnv * BM + wn * 64 + tn * 16 + fr];
    #pragma unroll
    for (int tm = 0; tm < 8; ++tm) {
      float4 xr = *(const float4*)(x2 + bmv * BM + wm * 128 + tm * 16 + fq * 4);
      #pragma unroll
      for (int tn = 0; tn < 4; ++tn) {
        acc[tm][tn][0] = -0.5f * xr.x + xch[tn];
        acc[tm][tn][1] = -0.5f * xr.y + xch[tn];
        acc[tm][tn][2] = -0.5f * xr.z + xch[tn];
        acc[tm][tn][3] = -0.5f * xr.w + xch[tn];
      }
    }
  };

  int cbm, cbn;
  decode_tile(xcd * TPX + lb, cbm, cbn);
  STAGE(cbm, cbn, 0, 0);
  STAGE(cbm, cbn, 1, 1);
  ACCINIT(cbm, cbn);
  int nbm = cbm, nbn = cbn;

  for (int j = 0; j < nslab; ++j) {
    const int bsel = j & 1;
    if (j + 1 < nslab) asm volatile("s_waitcnt vmcnt(8)" ::: "memory");
    else               asm volatile("s_waitcnt vmcnt(0)" ::: "memory");
    BAR();                                  // slab j readable by all waves

    // deferred block-reduce of the PREVIOUS tile (written before last BAR,
    // lgkmcnt-drained; next overwrite is >2 barriers away)
    if (bsel == 0 && j > 0 && tid == 0) {
      float bs = 0.f;
      #pragma unroll
      for (int w = 0; w < 8; ++w) bs += wsred[w];
      atomicAdd(accum, bs);
    }

    { // ---- compute slab j from buf[bsel]
      const unsigned char* A_s = As + bsel * 32768;
      const unsigned char* B_s = Bs + bsel * 32768;
      i32x8 bf[4];
      #pragma unroll
      for (int tn = 0; tn < 4; ++tn) {
        int row = wn * 64 + tn * 16 + fr;
        i32x4 lo = *(const i32x4*)(B_s + row * 128 + slotL);
        i32x4 hi = *(const i32x4*)(B_s + row * 128 + slotH);
        bf[tn] = __builtin_shufflevector(lo, hi, 0, 1, 2, 3, 4, 5, 6, 7);
      }
      #pragma unroll
      for (int tm = 0; tm < 8; ++tm) {
        int row = wm * 128 + tm * 16 + fr;
        i32x4 lo = *(const i32x4*)(A_s + row * 128 + slotL);
        i32x4 hi = *(const i32x4*)(A_s + row * 128 + slotH);
        i32x8 af = __builtin_shufflevector(lo, hi, 0, 1, 2, 3, 4, 5, 6, 7);
        #pragma unroll
        for (int tn = 0; tn < 4; ++tn)
          acc[tm][tn] = __builtin_amdgcn_mfma_scale_f32_16x16x128_f8f6f4(
              af, bf[tn], acc[tm][tn], 0, 0,
              0, 0x7F7F7F7F, 0, 0x7F7F7F7F);
      }
    }
    BAR();                                  // all waves done reading buf[bsel]

    if (j + 2 < nslab) {                    // prefetch slab j+2 into buf[bsel]
      if (bsel == 0) decode_tile(xcd * TPX + lb + 32 * ((j >> 1) + 1), nbm, nbn);
      STAGE(nbm, nbn, bsel /* == (j+2)&1 */, bsel);
    }

    if (bsel == 1) {
      // ---- epilogue for finished tile (cbm,cbn): acc = -d2/2
      float amax = -1e30f;
      #pragma unroll
      for (int tm = 0; tm < 8; ++tm)
        #pragma unroll
        for (int tn = 0; tn < 4; ++tn)
          #pragma unroll
          for (int v = 0; v < 4; ++v)
            amax = fmaxf(amax, acc[tm][tn][v]);

      float partial = 0.f;
      if (__any(amax > -40.f)) {            // diagonal tiles + freak near-pairs
        #pragma unroll
        for (int tm = 0; tm < 8; ++tm)
          #pragma unroll
          for (int tn = 0; tn < 4; ++tn)
            #pragma unroll
            for (int v = 0; v < 4; ++v) {
              float a = fminf(acc[tm][tn][v], 0.f);   // clamp d2 >= 0
              partial += exp2f(a * 2.885390082f);     // exp(2a)
            }
      }
      #pragma unroll
      for (int off = 32; off; off >>= 1) partial += __shfl_down(partial, off);
      float wgt = ((cbm < NB / 2) == (cbn < NB / 2)) ? 1.f : -1.f;
      if (cbm != cbn) wgt *= 2.f;           // off-diag: symmetry
      if (lane == 0) wsred[wid] = partial * wgt;
      asm volatile("s_waitcnt lgkmcnt(0)" ::: "memory");  // commit before next BAR

      if (j + 2 < nslab) { ACCINIT(nbm, nbn); cbm = nbm; cbn = nbn; }
    }
  }

  BAR();                                    // last tile's wsred visible
  if (tid == 0) {
    float bs = 0.f;
    #pragma unroll
    for (int w = 0; w < 8; ++w) bs += wsred[w];
    atomicAdd(accum, bs);
    __threadfence();                        // order adds before counter bump
    unsigned int old = atomicAdd(counter, 1u);
    if (old == NBLOCKS - 1) {               // last block: all adds L2-visible
      float tot = atomicAdd(accum, 0.f);    // coherent RMW read
      float mmd = tot / ((float)HALF * (float)HALF);
      out[0] = sqrtf(fmaxf(mmd, 0.f));
    }
  }
}

extern "C" void kernel_launch(void* const* d_in, const int* in_sizes, int n_in,
                              void* d_out, int out_size, void* d_ws, size_t ws_size,
                              hipStream_t stream) {
  const float* Nmat = (const float*)d_in[0];
  const float* Rmat = (const float*)d_in[1];
  float* out = (float*)d_out;

  char* ws = (char*)d_ws;
  unsigned char* Z = (unsigned char*)ws;                       // 4 MiB
  float* x2        = (float*)(ws + (size_t)MTOT * KDIM);       // 64 KiB
  float* accum     = (float*)(ws + (size_t)MTOT * KDIM + (size_t)MTOT * 4);
  unsigned int* counter = (unsigned int*)(ws + (size_t)MTOT * KDIM + (size_t)MTOT * 4 + 4);

  convert_kernel<<<MTOT / 4, 256, 0, stream>>>(Nmat, Rmat, (unsigned int*)Z, x2,
                                               accum, counter);
  mmd_gemm<<<NBLOCKS, 512, 0, stream>>>(Z, x2, accum, counter, out);
}